// Round 12
// baseline (1135.729 us; speedup 1.0000x reference)
//
#include <hip/hip_runtime.h>
#include <math.h>

// SchNet fused, round 12: r11 (512 thr / 8 waves, VGPR=128, no spills, 744us)
// with a perfectly balanced edge phase:
//   phase 1: tiles 0-31, NT=4 per wave, weight prefetch (all waves now PREF).
//   phase 2: tiles 32-34 split into 24 (tile, a-chunk) items = 3/wave with 3
//            independent MFMA chains (+1 barrier between its GEMM1/GEMM2).
// Max edge work/wave: 5 tiles -> 4.375 -> ~12% off the dominant phase.
//
// MFMA 16x16x32 bf16 layouts (HW-verified): A[m=lane&15][k=quad*8+j],
// B[k=quad*8+j][n=lane&15], C/D col(n)=lane&15, row(m)=quad*4+reg.
// All GEMMs transposed: D[outfeat][edge|atom] = W^T @ X^T so the C-layout
// matches the next GEMM's B-operand (edge/atom index stays on lane&15).

#define NTILES 35
#define HF32_OFF 0            // h fp32 [24 rows][512B], 16B-chunk XOR swizzled = 12288
#define EA_OFF   12288        // 35*4 subslots * 1024B = 143360 (EA / T1 fragments)
#define POOL_OFF 155648       // 6144: coords -> x -> agg -> T1node -> z
#define BIAS_OFF 161792       // e_b1|e_b2|n_b1|n_b2 fp32 = 2048
#define LDS_TOTAL 163840
// Intentional in-bounds overreads: hf32 rows 24-31 land in EA; pool rows 24-31
// and s=24 x-reads land in bias (max addr 163839) — garbage feeding only
// never-stored / never-aggregated output columns.

#define WLIN_F 0
#define EW1_F  32
#define EW2_F  64
#define NW1_F  96
#define NW2_F  128
#define GW1_F  160

typedef __attribute__((ext_vector_type(8))) short short8;
typedef __attribute__((ext_vector_type(4))) float floatx4;
typedef __attribute__((ext_vector_type(4))) unsigned uint4v;

#define MFMA(A,B,C) __builtin_amdgcn_mfma_f32_16x16x32_bf16((A),(B),(C),0,0,0)

#if __has_builtin(__builtin_amdgcn_cvt_pk_bf16_f32)
typedef __attribute__((ext_vector_type(2))) __bf16 bf16x2_t;
__device__ __forceinline__ unsigned pack2bf(float f0, float f1){
    bf16x2_t p = __builtin_amdgcn_cvt_pk_bf16_f32(f0, f1);
    return __builtin_bit_cast(unsigned, p);
}
#else
__device__ __forceinline__ unsigned pack2bf(float f0, float f1){  // RNE pair-pack
    unsigned u0 = __float_as_uint(f0), u1 = __float_as_uint(f1);
    u0 += 0x7FFFu + ((u0 >> 16) & 1u);
    u1 += 0x7FFFu + ((u1 >> 16) & 1u);
#if __has_builtin(__builtin_amdgcn_perm)
    return __builtin_amdgcn_perm(u1, u0, 0x07060302u);
#else
    return (u1 & 0xFFFF0000u) | (u0 >> 16);
#endif
}
#endif
__device__ __forceinline__ float blo(unsigned u){ return __uint_as_float(u << 16); }
__device__ __forceinline__ float bhi(unsigned u){ return __uint_as_float(u & 0xFFFF0000u); }
__device__ __forceinline__ short f2bf(float f){
    unsigned u = __float_as_uint(f);
    u += 0x7FFFu + ((u >> 16) & 1u);
    return (short)(u >> 16);
}
__device__ __forceinline__ float ssp2(float z){   // softplus(z) - ln2, log2 domain
#if __has_builtin(__builtin_amdgcn_exp2f)
    float e = __builtin_amdgcn_exp2f(z * 1.442695040888963f);
#else
    float e = exp2f(z * 1.442695040888963f);
#endif
#if __has_builtin(__builtin_amdgcn_logf)
    float l = __builtin_amdgcn_logf(1.0f + e);
#else
    float l = log2f(1.0f + e);
#endif
    return fmaf(l, 0.6931471805599453f, -0.6931471805599453f);
}
__device__ __forceinline__ short8 ld_ws(const char* __restrict__ ws, int fi, int lane){
    return *(const short8*)(ws + fi*1024 + lane*16);
}
// B-fragment from bf16 [24][256B] chunk-XOR-swizzled LDS table (no masking)
__device__ __forceinline__ short8 ld_bfrag(const char* base, int dt, int q, int quad, int mm){
    int d = dt*16 + mm;
    return *(const short8*)(base + d*256 + (((q*4 + quad) ^ (d & 15))*16));
}
// B-fragment from fp32 [24][512B] chunk-XOR-swizzled LDS h table (cvt on the fly)
__device__ __forceinline__ short8 ld_hfrag(const char* hf, int dt, int q, int quad, int mm){
    int d = dt*16 + mm;
    const char* base = hf + d*512;
    int c0 = q*8 + quad*2;
    floatx4 p0 = *(const floatx4*)(base + ((c0      ^ (d & 15))*16));
    floatx4 p1 = *(const floatx4*)(base + (((c0+1) ^ (d & 15))*16));
    uint4v u;
    u[0] = pack2bf(p0[0], p0[1]); u[1] = pack2bf(p0[2], p0[3]);
    u[2] = pack2bf(p1[0], p1[1]); u[3] = pack2bf(p1[2], p1[3]);
    return __builtin_bit_cast(short8, u);
}

// Edge-phase pass over NT wave-private tiles with weight prefetch.
template<int NT>
__device__ __forceinline__ void edge_tiles(char* ea, const char* __restrict__ ws,
                                           const char* pool, const float* bias,
                                           const int* tls, int lane, int quad, int mm)
{
    short8 frg[NT][4];
    #pragma unroll
    for (int ti = 0; ti < NT; ++ti)
        #pragma unroll
        for (int q = 0; q < 4; ++q)
            frg[ti][q] = *(const short8*)(ea + (tls[ti]*4 + q)*1024 + lane*16);

    // ---- GEMM1: T1 = ssp(e_w1^T @ EA^T + b1), in-place in B-frag layout ----
    {
        short8 wf[4];
        #pragma unroll
        for (int q = 0; q < 4; ++q) wf[q] = ld_ws(ws, EW1_F + q, lane);
        #pragma unroll 1
        for (int a = 0; a < 8; ++a){
            short8 wfn[4];
            int an = (a + 1) & 7;
            #pragma unroll
            for (int q = 0; q < 4; ++q) wfn[q] = ld_ws(ws, EW1_F + an*4 + q, lane);
            floatx4 bv = *(const floatx4*)(bias + a*16 + quad*4);
            floatx4 acc[NT];
            #pragma unroll
            for (int ti = 0; ti < NT; ++ti) acc[ti] = bv;
            #pragma unroll
            for (int q = 0; q < 4; ++q){
                #pragma unroll
                for (int ti = 0; ti < NT; ++ti) acc[ti] = MFMA(wf[q], frg[ti][q], acc[ti]);
            }
            int qp = a >> 1, coff = (((a & 1)*2 + (quad >> 1))*16 + mm)*16 + (quad & 1)*8;
            #pragma unroll
            for (int ti = 0; ti < NT; ++ti){
                uint2 pk;
                pk.x = pack2bf(ssp2(acc[ti][0]), ssp2(acc[ti][1]));
                pk.y = pack2bf(ssp2(acc[ti][2]), ssp2(acc[ti][3]));
                *(uint2*)(ea + (tls[ti]*4 + qp)*1024 + coff) = pk;
            }
            #pragma unroll
            for (int q = 0; q < 4; ++q) wf[q] = wfn[q];
        }
    }
    // ---- reload T1 fragments ----
    #pragma unroll
    for (int ti = 0; ti < NT; ++ti)
        #pragma unroll
        for (int q = 0; q < 4; ++q)
            frg[ti][q] = *(const short8*)(ea + (tls[ti]*4 + q)*1024 + lane*16);

    int s[NT];
    #pragma unroll
    for (int ti = 0; ti < NT; ++ti) s[ti] = (tls[ti]*16 + mm) / 23;

    // ---- GEMM2: EA = (e_w2^T @ T1^T + b2) * x[s], in-place in B-frag layout ----
    {
        short8 wf[4];
        #pragma unroll
        for (int q = 0; q < 4; ++q) wf[q] = ld_ws(ws, EW2_F + q, lane);
        #pragma unroll 1
        for (int a = 0; a < 8; ++a){
            short8 wfn[4];
            int an = (a + 1) & 7;
            #pragma unroll
            for (int q = 0; q < 4; ++q) wfn[q] = ld_ws(ws, EW2_F + an*4 + q, lane);
            floatx4 bv = *(const floatx4*)(bias + 128 + a*16 + quad*4);
            floatx4 acc[NT];
            #pragma unroll
            for (int ti = 0; ti < NT; ++ti) acc[ti] = bv;
            #pragma unroll
            for (int q = 0; q < 4; ++q){
                #pragma unroll
                for (int ti = 0; ti < NT; ++ti) acc[ti] = MFMA(wf[q], frg[ti][q], acc[ti]);
            }
            int qp = a >> 1, coff = (((a & 1)*2 + (quad >> 1))*16 + mm)*16 + (quad & 1)*8;
            int xoff = (a*16 + quad*4)*2;
            #pragma unroll
            for (int ti = 0; ti < NT; ++ti){
                uint2 xv = *(const uint2*)(pool + s[ti]*256 + xoff);
                uint2 pk;
                pk.x = pack2bf(acc[ti][0]*blo(xv.x), acc[ti][1]*bhi(xv.x));
                pk.y = pack2bf(acc[ti][2]*blo(xv.y), acc[ti][3]*bhi(xv.y));
                *(uint2*)(ea + (tls[ti]*4 + qp)*1024 + coff) = pk;
            }
            #pragma unroll
            for (int q = 0; q < 4; ++q) wf[q] = wfn[q];
        }
    }
}

__global__ __launch_bounds__(64) void prep_frags(
    const float* __restrict__ wlin, const float* __restrict__ ew1,
    const float* __restrict__ ew2,  const float* __restrict__ nw1,
    const float* __restrict__ nw2,  const float* __restrict__ gw1,
    char* __restrict__ ws)
{
    int f = blockIdx.x;                 // 0..175
    int lane = threadIdx.x;
    int quad = lane >> 4, mm = lane & 15;
    const float* W; int ncols, a, q;
    if (f < 160){
        int m = f >> 5, r = f & 31; a = r >> 2; q = r & 3; ncols = 128;
        W = (m==0) ? wlin : (m==1) ? ew1 : (m==2) ? ew2 : (m==3) ? nw1 : nw2;
    } else {
        int r = f - 160; a = r >> 2; q = r & 3; ncols = 64; W = gw1;
    }
    short8 frag;
    #pragma unroll
    for (int j = 0; j < 8; ++j)
        frag[j] = f2bf(W[(q*32 + quad*8 + j)*ncols + a*16 + mm]);
    *(short8*)(ws + f*1024 + lane*16) = frag;
}

__global__ __launch_bounds__(512, 2) void schnet_fused(
    const int*   __restrict__ charges, const float* __restrict__ coords,
    const float* __restrict__ emb,     const char*  __restrict__ ws,
    const float* __restrict__ e_b1,    const float* __restrict__ e_b2,
    const float* __restrict__ n_b1,    const float* __restrict__ n_b2,
    const float* __restrict__ g_b1,    const float* __restrict__ g_w2,
    const float* __restrict__ g_b2,
    float* __restrict__ out)
{
    __shared__ char smem[LDS_TOTAL];

    const int mol  = blockIdx.x;
    const int tid  = threadIdx.x;
    const int wv   = tid >> 6;          // 0..7
    const int lane = tid & 63;
    const int quad = lane >> 4;
    const int mm   = lane & 15;

    char*  hf   = smem + HF32_OFF;
    char*  ea   = smem + EA_OFF;
    char*  pool = smem + POOL_OFF;
    float* bias = (float*)(smem + BIAS_OFF);

    if (tid < 72) ((float*)pool)[tid] = coords[mol*72 + tid];
    {
        int which = tid >> 7, j = tid & 127;
        const float* src = (which==0) ? e_b1 : (which==1) ? e_b2 : (which==2) ? n_b1 : n_b2;
        bias[tid] = src[j];
    }

    // h init: fp32 into LDS, chunk-XOR swizzled. task = (a | dt<<3), 2 per wave
    #pragma unroll
    for (int ts = 0; ts < 2; ++ts){
        int task = wv + ts*8;
        int a = task & 7, dt = task >> 3, d = dt*16 + mm;
        if (d < 24){
            int ch = charges[mol*24 + d];
            floatx4 ev = *(const floatx4*)(emb + (size_t)ch*128 + a*16 + quad*4);
            *(floatx4*)(hf + d*512 + (((a*4 + quad) ^ (d & 15))*16)) = ev;
        }
    }
    __syncthreads();

    {   // RBF -> EA B-fragments (t = wv + 8*ti)
        const float stepv = 10.0f/127.0f;
        const float coeff = -0.5f/(stepv*stepv);
        const float* cs = (const float*)pool;
        #pragma unroll
        for (int ti = 0; ti < 5; ++ti){
            int t = wv + 8*ti;
            if (t < NTILES){
                int e = t*16 + mm; if (e > 551) e = 551;
                int s = e/23, dl = e - s*23; int d = dl + (dl >= s ? 1 : 0);
                float dx = cs[s*3+0]-cs[d*3+0], dy = cs[s*3+1]-cs[d*3+1], dz = cs[s*3+2]-cs[d*3+2];
                float dist = sqrtf(dx*dx + dy*dy + dz*dz);
                #pragma unroll
                for (int q = 0; q < 4; ++q){
                    float v[8];
                    #pragma unroll
                    for (int j = 0; j < 8; ++j){
                        float td = dist - (float)(q*32 + quad*8 + j)*stepv;
#if __has_builtin(__builtin_amdgcn_exp2f)
                        v[j] = __builtin_amdgcn_exp2f(coeff*td*td*1.442695040888963f);
#else
                        v[j] = expf(coeff*td*td);
#endif
                    }
                    uint4 pk;
                    pk.x = pack2bf(v[0],v[1]); pk.y = pack2bf(v[2],v[3]);
                    pk.z = pack2bf(v[4],v[5]); pk.w = pack2bf(v[6],v[7]);
                    *(uint4*)(ea + (t*4 + q)*1024 + lane*16) = pk;
                }
            }
        }
    }
    __syncthreads();

    for (int layer = 0; layer < 4; ++layer){
        {   // x = h @ wlin -> pool bf16 [24][256B] linear; 2 tasks/wave
            #pragma unroll
            for (int ts = 0; ts < 2; ++ts){
                int task = wv + ts*8;
                int a = task & 7, dt = task >> 3;
                floatx4 acc = 0;
                #pragma unroll
                for (int q = 0; q < 4; ++q){
                    short8 wf = ld_ws(ws, WLIN_F + a*4 + q, lane);
                    short8 hfr = ld_hfrag(hf, dt, q, quad, mm);
                    acc = MFMA(wf, hfr, acc);
                }
                int d = dt*16 + mm;
                if (d < 24){
                    uint2 pk; pk.x = pack2bf(acc[0], acc[1]); pk.y = pack2bf(acc[2], acc[3]);
                    *(uint2*)(pool + d*256 + (a*16 + quad*4)*2) = pk;
                }
            }
        }
        __syncthreads();

        {   // edge phase 1: tiles 0..31, 4 per wave, prefetched
            int tls[4] = {wv, wv + 8, wv + 16, wv + 24};
            edge_tiles<4>(ea, ws, pool, bias, tls, lane, quad, mm);
        }
        {   // edge phase 2: tiles 32-34 as 24 (tile, a) items, 3 per wave
            int ta[3], aa[3];
            short8 frgP[3][4];
            #pragma unroll
            for (int i = 0; i < 3; ++i){
                int item = wv*3 + i;
                ta[i] = 32 + (item >> 3);
                aa[i] = item & 7;
            }
            #pragma unroll
            for (int i = 0; i < 3; ++i)
                #pragma unroll
                for (int q = 0; q < 4; ++q)
                    frgP[i][q] = *(const short8*)(ea + (ta[i]*4 + q)*1024 + lane*16);
            // GEMM1 for 3 items
            {
                floatx4 acc[3];
                #pragma unroll
                for (int i = 0; i < 3; ++i)
                    acc[i] = *(const floatx4*)(bias + aa[i]*16 + quad*4);
                #pragma unroll
                for (int q = 0; q < 4; ++q){
                    #pragma unroll
                    for (int i = 0; i < 3; ++i){
                        short8 wf = ld_ws(ws, EW1_F + aa[i]*4 + q, lane);
                        acc[i] = MFMA(wf, frgP[i][q], acc[i]);
                    }
                }
                #pragma unroll
                for (int i = 0; i < 3; ++i){
                    int qp = aa[i] >> 1;
                    int coff = (((aa[i] & 1)*2 + (quad >> 1))*16 + mm)*16 + (quad & 1)*8;
                    uint2 pk;
                    pk.x = pack2bf(ssp2(acc[i][0]), ssp2(acc[i][1]));
                    pk.y = pack2bf(ssp2(acc[i][2]), ssp2(acc[i][3]));
                    *(uint2*)(ea + (ta[i]*4 + qp)*1024 + coff) = pk;
                }
            }
            __syncthreads();    // T1 of tiles 32-34 complete (written by mixed waves)
            #pragma unroll
            for (int i = 0; i < 3; ++i)
                #pragma unroll
                for (int q = 0; q < 4; ++q)
                    frgP[i][q] = *(const short8*)(ea + (ta[i]*4 + q)*1024 + lane*16);
            // GEMM2 for 3 items
            {
                floatx4 acc[3];
                #pragma unroll
                for (int i = 0; i < 3; ++i)
                    acc[i] = *(const floatx4*)(bias + 128 + aa[i]*16 + quad*4);
                #pragma unroll
                for (int q = 0; q < 4; ++q){
                    #pragma unroll
                    for (int i = 0; i < 3; ++i){
                        short8 wf = ld_ws(ws, EW2_F + aa[i]*4 + q, lane);
                        acc[i] = MFMA(wf, frgP[i][q], acc[i]);
                    }
                }
                #pragma unroll
                for (int i = 0; i < 3; ++i){
                    int s = (ta[i]*16 + mm) / 23;       // s=24 for garbage edges: in-bounds bias read
                    int qp = aa[i] >> 1;
                    int coff = (((aa[i] & 1)*2 + (quad >> 1))*16 + mm)*16 + (quad & 1)*8;
                    uint2 xv = *(const uint2*)(pool + s*256 + (aa[i]*16 + quad*4)*2);
                    uint2 pk;
                    pk.x = pack2bf(acc[i][0]*blo(xv.x), acc[i][1]*bhi(xv.x));
                    pk.y = pack2bf(acc[i][2]*blo(xv.y), acc[i][3]*bhi(xv.y));
                    *(uint2*)(ea + (ta[i]*4 + qp)*1024 + coff) = pk;
                }
            }
        }
        __syncthreads();

        {   // agg[d][f] = sum_s EA[e(s,d)][f] -> pool; 3 d's per wave
            int c = lane & 15, sg = lane >> 4;
            #pragma unroll
            for (int u = 0; u < 3; ++u){
                int d = wv + 8*u;
                float av[8] = {0,0,0,0,0,0,0,0};
                #pragma unroll
                for (int tt = 0; tt < 6; ++tt){
                    int s2 = sg + 4*tt;
                    int e  = s2*23 + d - (d > s2 ? 1 : 0);
                    float msk = (s2 != d) ? 1.f : 0.f;
                    uint4 v = *(const uint4*)(ea + ((e >> 4)*4 + (c >> 2))*1024
                                              + (((c & 3)*16 + (e & 15))*16));
                    av[0] += msk*blo(v.x); av[1] += msk*bhi(v.x);
                    av[2] += msk*blo(v.y); av[3] += msk*bhi(v.y);
                    av[4] += msk*blo(v.z); av[5] += msk*bhi(v.z);
                    av[6] += msk*blo(v.w); av[7] += msk*bhi(v.w);
                }
                #pragma unroll
                for (int j = 0; j < 8; ++j){
                    av[j] += __shfl_xor(av[j], 32);
                    av[j] += __shfl_xor(av[j], 16);
                }
                if (sg == 0){
                    uint4 pk;
                    pk.x = pack2bf(av[0],av[1]); pk.y = pack2bf(av[2],av[3]);
                    pk.z = pack2bf(av[4],av[5]); pk.w = pack2bf(av[6],av[7]);
                    *(uint4*)(pool + d*256 + ((c ^ (d & 15))*16)) = pk;
                }
            }
        }
        __syncthreads();

        {   // node MLP: h += ssp(agg@n_w1+b1)@n_w2+b2   (h: fp32 LDS RMW)
            floatx4 accN[2];
            #pragma unroll
            for (int ts = 0; ts < 2; ++ts){
                int task = wv + ts*8;
                int a = task & 7, dt = task >> 3;
                accN[ts] = *(const floatx4*)(bias + 256 + a*16 + quad*4);
                #pragma unroll
                for (int q = 0; q < 4; ++q){
                    short8 wf = ld_ws(ws, NW1_F + a*4 + q, lane);
                    short8 af = ld_bfrag(pool, dt, q, quad, mm);
                    accN[ts] = MFMA(wf, af, accN[ts]);
                }
            }
            __syncthreads();    // agg reads complete before T1node overwrites pool
            #pragma unroll
            for (int ts = 0; ts < 2; ++ts){
                int task = wv + ts*8;
                int a = task & 7, dt = task >> 3, d = dt*16 + mm;
                if (d < 24){
                    int cc = a*2 + (quad >> 1), off8 = (quad & 1)*8;
                    uint2 pk;
                    pk.x = pack2bf(ssp2(accN[ts][0]), ssp2(accN[ts][1]));
                    pk.y = pack2bf(ssp2(accN[ts][2]), ssp2(accN[ts][3]));
                    *(uint2*)(pool + d*256 + ((cc ^ (d & 15))*16) + off8) = pk;
                }
            }
            __syncthreads();
            #pragma unroll
            for (int ts = 0; ts < 2; ++ts){
                int task = wv + ts*8;
                int a = task & 7, dt = task >> 3;
                floatx4 acc2 = *(const floatx4*)(bias + 384 + a*16 + quad*4);
                #pragma unroll
                for (int q = 0; q < 4; ++q){
                    short8 wf = ld_ws(ws, NW2_F + a*4 + q, lane);
                    short8 tf = ld_bfrag(pool, dt, q, quad, mm);
                    acc2 = MFMA(wf, tf, acc2);
                }
                int d = dt*16 + mm;
                if (d < 24){
                    char* ha = hf + d*512 + (((a*4 + quad) ^ (d & 15))*16);
                    floatx4 hv = *(floatx4*)ha;
                    #pragma unroll
                    for (int r = 0; r < 4; ++r) hv[r] += acc2[r];
                    *(floatx4*)ha = hv;
                }
            }
        }
        __syncthreads();
    } // layers

    {   // graph head: out[mol] = sum_d (ssp(h@g_w1+b1)@g_w2 + b2); 1 task/wave
        {
            int a = wv & 3, dt = wv >> 2;
            floatx4 acc = *(const floatx4*)(g_b1 + a*16 + quad*4);
            #pragma unroll
            for (int q = 0; q < 4; ++q){
                short8 gf = ld_ws(ws, GW1_F + a*4 + q, lane);
                short8 hfr = ld_hfrag(hf, dt, q, quad, mm);
                acc = MFMA(gf, hfr, acc);
            }
            int d = dt*16 + mm;
            if (d < 24){
                uint2 pk;
                pk.x = pack2bf(ssp2(acc[0]), ssp2(acc[1]));
                pk.y = pack2bf(ssp2(acc[2]), ssp2(acc[3]));
                *(uint2*)(pool + d*128 + (a*16 + quad*4)*2) = pk;   // z[24][64] bf16
            }
        }
        __syncthreads();
        if (tid < 48){
            int dd = tid >> 1, half = tid & 1;
            float v = 0.f;
            const unsigned* zr = (const unsigned*)(pool + dd*128 + half*64);
            #pragma unroll
            for (int j = 0; j < 16; ++j){
                unsigned u = zr[j];
                v += blo(u) * g_w2[half*32 + 2*j] + bhi(u) * g_w2[half*32 + 2*j + 1];
            }
            v += __shfl_xor(v, 1);
            if (half == 0) ((float*)(pool + 4096))[dd] = v;
        }
        __syncthreads();
        if (tid == 0){
            float sum = 0.f;
            #pragma unroll
            for (int dd = 0; dd < 24; ++dd) sum += ((float*)(pool + 4096))[dd];
            out[mol] = sum + 24.0f * g_b2[0];
        }
    }
}

extern "C" void kernel_launch(void* const* d_in, const int* in_sizes, int n_in,
                              void* d_out, int out_size, void* d_ws, size_t ws_size,
                              hipStream_t stream) {
    const int*   charges = (const int*)d_in[0];
    const float* coords  = (const float*)d_in[1];
    const float* emb  = (const float*)d_in[4];
    const float* wlin = (const float*)d_in[5];
    const float* ew1  = (const float*)d_in[6];
    const float* eb1  = (const float*)d_in[7];
    const float* ew2  = (const float*)d_in[8];
    const float* eb2  = (const float*)d_in[9];
    const float* nw1  = (const float*)d_in[10];
    const float* nb1  = (const float*)d_in[11];
    const float* nw2  = (const float*)d_in[12];
    const float* nb2  = (const float*)d_in[13];
    const float* gw1  = (const float*)d_in[14];
    const float* gb1  = (const float*)d_in[15];
    const float* gw2  = (const float*)d_in[16];
    const float* gb2  = (const float*)d_in[17];
    float* out = (float*)d_out;
    char* ws = (char*)d_ws;                 // 176 KB of bf16 weight fragments

    prep_frags<<<176, 64, 0, stream>>>(wlin, ew1, ew2, nw1, nw2, gw1, ws);

    schnet_fused<<<2048, 512, 0, stream>>>(
        charges, coords, emb, ws, eb1, eb2, nb1, nb2, gb1, gw2, gb2, out);
}

// Round 13
// 713.901 us; speedup vs baseline: 1.5909x; 1.5909x over previous
//
#include <hip/hip_runtime.h>
#include <math.h>

// SchNet fused, round 13: r11 (744us: 512 thr / 8 waves, VGPR=128, no spills,
// NT=5/NT=4 edge split — per-SIMD tile totals 9/9/9/8, near-balanced) plus a
// bank-conflict fix for the agg phase. r12's phase-2 rebalance is REVERTED
// (it re-introduced spills: frgP coexisted with phase-1 live set -> 1.6GB scratch).
//
// Conflict fix: agg's 16 same-edge lanes hit one 4-bank group (subslot stride
// 1024 and chunk stride 256 are both 0 mod 128B; bank depends only on e&7) ->
// 16-way conflict, ~6.1e7 cycles (~13% of runtime). EA in-subslot layout now
// XOR-swizzles the row index: chunk (q,row,mm) at (row*16 + (mm^row*2^(q&1)))*16.
// Bijective per (q,row); applied at all 5 EA access sites -> bit-exact.
//
// MFMA 16x16x32 bf16 layouts (HW-verified): A[m=lane&15][k=quad*8+j],
// B[k=quad*8+j][n=lane&15], C/D col(n)=lane&15, row(m)=quad*4+reg.
// All GEMMs transposed: D[outfeat][edge|atom] = W^T @ X^T.

#define NTILES 35
#define HF32_OFF 0            // h fp32 [24 rows][512B], 16B-chunk XOR swizzled = 12288
#define EA_OFF   12288        // 35*4 subslots * 1024B = 143360 (EA / T1 fragments)
#define POOL_OFF 155648       // 6144: coords -> x -> agg -> T1node -> z
#define BIAS_OFF 161792       // e_b1|e_b2|n_b1|n_b2 fp32 = 2048
#define LDS_TOTAL 163840

#define WLIN_F 0
#define EW1_F  32
#define EW2_F  64
#define NW1_F  96
#define NW2_F  128
#define GW1_F  160

typedef __attribute__((ext_vector_type(8))) short short8;
typedef __attribute__((ext_vector_type(4))) float floatx4;
typedef __attribute__((ext_vector_type(4))) unsigned uint4v;

#define MFMA(A,B,C) __builtin_amdgcn_mfma_f32_16x16x32_bf16((A),(B),(C),0,0,0)

#if __has_builtin(__builtin_amdgcn_cvt_pk_bf16_f32)
typedef __attribute__((ext_vector_type(2))) __bf16 bf16x2_t;
__device__ __forceinline__ unsigned pack2bf(float f0, float f1){
    bf16x2_t p = __builtin_amdgcn_cvt_pk_bf16_f32(f0, f1);
    return __builtin_bit_cast(unsigned, p);
}
#else
__device__ __forceinline__ unsigned pack2bf(float f0, float f1){  // RNE pair-pack
    unsigned u0 = __float_as_uint(f0), u1 = __float_as_uint(f1);
    u0 += 0x7FFFu + ((u0 >> 16) & 1u);
    u1 += 0x7FFFu + ((u1 >> 16) & 1u);
#if __has_builtin(__builtin_amdgcn_perm)
    return __builtin_amdgcn_perm(u1, u0, 0x07060302u);
#else
    return (u1 & 0xFFFF0000u) | (u0 >> 16);
#endif
}
#endif
__device__ __forceinline__ float blo(unsigned u){ return __uint_as_float(u << 16); }
__device__ __forceinline__ float bhi(unsigned u){ return __uint_as_float(u & 0xFFFF0000u); }
__device__ __forceinline__ short f2bf(float f){
    unsigned u = __float_as_uint(f);
    u += 0x7FFFu + ((u >> 16) & 1u);
    return (short)(u >> 16);
}
__device__ __forceinline__ float ssp2(float z){   // softplus(z) - ln2, log2 domain
#if __has_builtin(__builtin_amdgcn_exp2f)
    float e = __builtin_amdgcn_exp2f(z * 1.442695040888963f);
#else
    float e = exp2f(z * 1.442695040888963f);
#endif
#if __has_builtin(__builtin_amdgcn_logf)
    float l = __builtin_amdgcn_logf(1.0f + e);
#else
    float l = log2f(1.0f + e);
#endif
    return fmaf(l, 0.6931471805599453f, -0.6931471805599453f);
}
// EA in-subslot row swizzle: chunk (subslot q, row, mm) lives at
// (row*16 + (mm ^ row*2 ^ (q&1)))*16. Spreads agg's same-mm reads over 8 bank groups.
__device__ __forceinline__ int eswz(int q, int row, int mm){
    return (row*16 + (mm ^ (row*2) ^ (q & 1)))*16;
}
__device__ __forceinline__ short8 ld_ws(const char* __restrict__ ws, int fi, int lane){
    return *(const short8*)(ws + fi*1024 + lane*16);
}
// B-fragment from bf16 [24][256B] chunk-XOR-swizzled LDS table (no masking)
__device__ __forceinline__ short8 ld_bfrag(const char* base, int dt, int q, int quad, int mm){
    int d = dt*16 + mm;
    return *(const short8*)(base + d*256 + (((q*4 + quad) ^ (d & 15))*16));
}
// B-fragment from fp32 [24][512B] chunk-XOR-swizzled LDS h table (cvt on the fly)
__device__ __forceinline__ short8 ld_hfrag(const char* hf, int dt, int q, int quad, int mm){
    int d = dt*16 + mm;
    const char* base = hf + d*512;
    int c0 = q*8 + quad*2;
    floatx4 p0 = *(const floatx4*)(base + ((c0      ^ (d & 15))*16));
    floatx4 p1 = *(const floatx4*)(base + (((c0+1) ^ (d & 15))*16));
    uint4v u;
    u[0] = pack2bf(p0[0], p0[1]); u[1] = pack2bf(p0[2], p0[3]);
    u[2] = pack2bf(p1[0], p1[1]); u[3] = pack2bf(p1[2], p1[3]);
    return __builtin_bit_cast(short8, u);
}

// Edge-phase pass over NT tiles: EA_tile = x[s] * (ssp(EA@w1+b1)@w2+b2)
// PREF: software-pipeline the next a-iteration's weight fragments (+16 VGPRs).
template<int NT, bool PREF>
__device__ __forceinline__ void edge_tiles(char* ea, const char* __restrict__ ws,
                                           const char* pool, const float* bias,
                                           const int* tls, int lane, int quad, int mm)
{
    short8 frg[NT][4];
    #pragma unroll
    for (int ti = 0; ti < NT; ++ti)
        #pragma unroll
        for (int q = 0; q < 4; ++q)
            frg[ti][q] = *(const short8*)(ea + (tls[ti]*4 + q)*1024 + eswz(q, quad, mm));

    // ---- GEMM1: T1 = ssp(e_w1^T @ EA^T + b1), in-place in B-frag layout ----
    {
        short8 wf[4];
        #pragma unroll
        for (int q = 0; q < 4; ++q) wf[q] = ld_ws(ws, EW1_F + q, lane);
        #pragma unroll 1
        for (int a = 0; a < 8; ++a){
            short8 wfn[4];
            if (PREF){
                int an = (a + 1) & 7;
                #pragma unroll
                for (int q = 0; q < 4; ++q) wfn[q] = ld_ws(ws, EW1_F + an*4 + q, lane);
            }
            floatx4 bv = *(const floatx4*)(bias + a*16 + quad*4);
            floatx4 acc[NT];
            #pragma unroll
            for (int ti = 0; ti < NT; ++ti) acc[ti] = bv;
            #pragma unroll
            for (int q = 0; q < 4; ++q){
                short8 w = PREF ? wf[q] : ld_ws(ws, EW1_F + a*4 + q, lane);
                #pragma unroll
                for (int ti = 0; ti < NT; ++ti) acc[ti] = MFMA(w, frg[ti][q], acc[ti]);
            }
            int qp = a >> 1, qq = (a & 1)*2 + (quad >> 1);
            int coff = eswz(qp, qq, mm) + (quad & 1)*8;
            #pragma unroll
            for (int ti = 0; ti < NT; ++ti){
                uint2 pk;
                pk.x = pack2bf(ssp2(acc[ti][0]), ssp2(acc[ti][1]));
                pk.y = pack2bf(ssp2(acc[ti][2]), ssp2(acc[ti][3]));
                *(uint2*)(ea + (tls[ti]*4 + qp)*1024 + coff) = pk;
            }
            if (PREF){
                #pragma unroll
                for (int q = 0; q < 4; ++q) wf[q] = wfn[q];
            }
        }
    }
    // ---- reload T1 fragments ----
    #pragma unroll
    for (int ti = 0; ti < NT; ++ti)
        #pragma unroll
        for (int q = 0; q < 4; ++q)
            frg[ti][q] = *(const short8*)(ea + (tls[ti]*4 + q)*1024 + eswz(q, quad, mm));

    int s[NT];
    #pragma unroll
    for (int ti = 0; ti < NT; ++ti) s[ti] = (tls[ti]*16 + mm) / 23;

    // ---- GEMM2: EA = (e_w2^T @ T1^T + b2) * x[s], in-place in B-frag layout ----
    {
        short8 wf[4];
        #pragma unroll
        for (int q = 0; q < 4; ++q) wf[q] = ld_ws(ws, EW2_F + q, lane);
        #pragma unroll 1
        for (int a = 0; a < 8; ++a){
            short8 wfn[4];
            if (PREF){
                int an = (a + 1) & 7;
                #pragma unroll
                for (int q = 0; q < 4; ++q) wfn[q] = ld_ws(ws, EW2_F + an*4 + q, lane);
            }
            floatx4 bv = *(const floatx4*)(bias + 128 + a*16 + quad*4);
            floatx4 acc[NT];
            #pragma unroll
            for (int ti = 0; ti < NT; ++ti) acc[ti] = bv;
            #pragma unroll
            for (int q = 0; q < 4; ++q){
                short8 w = PREF ? wf[q] : ld_ws(ws, EW2_F + a*4 + q, lane);
                #pragma unroll
                for (int ti = 0; ti < NT; ++ti) acc[ti] = MFMA(w, frg[ti][q], acc[ti]);
            }
            int qp = a >> 1, qq = (a & 1)*2 + (quad >> 1);
            int coff = eswz(qp, qq, mm) + (quad & 1)*8;
            int xoff = (a*16 + quad*4)*2;
            #pragma unroll
            for (int ti = 0; ti < NT; ++ti){
                uint2 xv = *(const uint2*)(pool + s[ti]*256 + xoff);
                uint2 pk;
                pk.x = pack2bf(acc[ti][0]*blo(xv.x), acc[ti][1]*bhi(xv.x));
                pk.y = pack2bf(acc[ti][2]*blo(xv.y), acc[ti][3]*bhi(xv.y));
                *(uint2*)(ea + (tls[ti]*4 + qp)*1024 + coff) = pk;
            }
            if (PREF){
                #pragma unroll
                for (int q = 0; q < 4; ++q) wf[q] = wfn[q];
            }
        }
    }
}

__global__ __launch_bounds__(64) void prep_frags(
    const float* __restrict__ wlin, const float* __restrict__ ew1,
    const float* __restrict__ ew2,  const float* __restrict__ nw1,
    const float* __restrict__ nw2,  const float* __restrict__ gw1,
    char* __restrict__ ws)
{
    int f = blockIdx.x;                 // 0..175
    int lane = threadIdx.x;
    int quad = lane >> 4, mm = lane & 15;
    const float* W; int ncols, a, q;
    if (f < 160){
        int m = f >> 5, r = f & 31; a = r >> 2; q = r & 3; ncols = 128;
        W = (m==0) ? wlin : (m==1) ? ew1 : (m==2) ? ew2 : (m==3) ? nw1 : nw2;
    } else {
        int r = f - 160; a = r >> 2; q = r & 3; ncols = 64; W = gw1;
    }
    short8 frag;
    #pragma unroll
    for (int j = 0; j < 8; ++j)
        frag[j] = f2bf(W[(q*32 + quad*8 + j)*ncols + a*16 + mm]);
    *(short8*)(ws + f*1024 + lane*16) = frag;
}

__global__ __launch_bounds__(512, 2) void schnet_fused(
    const int*   __restrict__ charges, const float* __restrict__ coords,
    const float* __restrict__ emb,     const char*  __restrict__ ws,
    const float* __restrict__ e_b1,    const float* __restrict__ e_b2,
    const float* __restrict__ n_b1,    const float* __restrict__ n_b2,
    const float* __restrict__ g_b1,    const float* __restrict__ g_w2,
    const float* __restrict__ g_b2,
    float* __restrict__ out)
{
    __shared__ char smem[LDS_TOTAL];

    const int mol  = blockIdx.x;
    const int tid  = threadIdx.x;
    const int wv   = tid >> 6;          // 0..7
    const int lane = tid & 63;
    const int quad = lane >> 4;
    const int mm   = lane & 15;

    char*  hf   = smem + HF32_OFF;
    char*  ea   = smem + EA_OFF;
    char*  pool = smem + POOL_OFF;
    float* bias = (float*)(smem + BIAS_OFF);

    if (tid < 72) ((float*)pool)[tid] = coords[mol*72 + tid];
    {
        int which = tid >> 7, j = tid & 127;
        const float* src = (which==0) ? e_b1 : (which==1) ? e_b2 : (which==2) ? n_b1 : n_b2;
        bias[tid] = src[j];
    }

    // h init: fp32 into LDS, chunk-XOR swizzled. task = (a | dt<<3), 2 per wave
    #pragma unroll
    for (int ts = 0; ts < 2; ++ts){
        int task = wv + ts*8;
        int a = task & 7, dt = task >> 3, d = dt*16 + mm;
        if (d < 24){
            int ch = charges[mol*24 + d];
            floatx4 ev = *(const floatx4*)(emb + (size_t)ch*128 + a*16 + quad*4);
            *(floatx4*)(hf + d*512 + (((a*4 + quad) ^ (d & 15))*16)) = ev;
        }
    }
    __syncthreads();

    {   // RBF -> EA B-fragments (t = wv + 8*ti)
        const float stepv = 10.0f/127.0f;
        const float coeff = -0.5f/(stepv*stepv);
        const float* cs = (const float*)pool;
        #pragma unroll
        for (int ti = 0; ti < 5; ++ti){
            int t = wv + 8*ti;
            if (t < NTILES){
                int e = t*16 + mm; if (e > 551) e = 551;
                int s = e/23, dl = e - s*23; int d = dl + (dl >= s ? 1 : 0);
                float dx = cs[s*3+0]-cs[d*3+0], dy = cs[s*3+1]-cs[d*3+1], dz = cs[s*3+2]-cs[d*3+2];
                float dist = sqrtf(dx*dx + dy*dy + dz*dz);
                #pragma unroll
                for (int q = 0; q < 4; ++q){
                    float v[8];
                    #pragma unroll
                    for (int j = 0; j < 8; ++j){
                        float td = dist - (float)(q*32 + quad*8 + j)*stepv;
#if __has_builtin(__builtin_amdgcn_exp2f)
                        v[j] = __builtin_amdgcn_exp2f(coeff*td*td*1.442695040888963f);
#else
                        v[j] = expf(coeff*td*td);
#endif
                    }
                    uint4 pk;
                    pk.x = pack2bf(v[0],v[1]); pk.y = pack2bf(v[2],v[3]);
                    pk.z = pack2bf(v[4],v[5]); pk.w = pack2bf(v[6],v[7]);
                    *(uint4*)(ea + (t*4 + q)*1024 + eswz(q, quad, mm)) = pk;
                }
            }
        }
    }
    __syncthreads();

    for (int layer = 0; layer < 4; ++layer){
        {   // x = h @ wlin -> pool bf16 [24][256B] linear; 2 tasks/wave
            #pragma unroll
            for (int ts = 0; ts < 2; ++ts){
                int task = wv + ts*8;
                int a = task & 7, dt = task >> 3;
                floatx4 acc = 0;
                #pragma unroll
                for (int q = 0; q < 4; ++q){
                    short8 wf = ld_ws(ws, WLIN_F + a*4 + q, lane);
                    short8 hfr = ld_hfrag(hf, dt, q, quad, mm);
                    acc = MFMA(wf, hfr, acc);
                }
                int d = dt*16 + mm;
                if (d < 24){
                    uint2 pk; pk.x = pack2bf(acc[0], acc[1]); pk.y = pack2bf(acc[2], acc[3]);
                    *(uint2*)(pool + d*256 + (a*16 + quad*4)*2) = pk;
                }
            }
        }
        __syncthreads();

        {   // edge phase: single balanced pass. waves 0-2: 5 tiles, waves 3-7: 4.
            if (wv < 3){
                int tls[5] = {wv, wv + 8, wv + 16, wv + 24, 32 + wv};
                edge_tiles<5, false>(ea, ws, pool, bias, tls, lane, quad, mm);
            } else {
                int tls[4] = {wv, wv + 8, wv + 16, wv + 24};
                edge_tiles<4, true>(ea, ws, pool, bias, tls, lane, quad, mm);
            }
        }
        __syncthreads();

        {   // agg[d][f] = sum_s EA[e(s,d)][f] -> pool; 3 d's per wave
            int c = lane & 15, sg = lane >> 4;
            int qA = c >> 2, quadA = c & 3;
            #pragma unroll
            for (int u = 0; u < 3; ++u){
                int d = wv + 8*u;
                float av[8] = {0,0,0,0,0,0,0,0};
                #pragma unroll
                for (int tt = 0; tt < 6; ++tt){
                    int s2 = sg + 4*tt;
                    int e  = s2*23 + d - (d > s2 ? 1 : 0);
                    float msk = (s2 != d) ? 1.f : 0.f;
                    uint4 v = *(const uint4*)(ea + ((e >> 4)*4 + qA)*1024
                                              + eswz(qA, quadA, e & 15));
                    av[0] += msk*blo(v.x); av[1] += msk*bhi(v.x);
                    av[2] += msk*blo(v.y); av[3] += msk*bhi(v.y);
                    av[4] += msk*blo(v.z); av[5] += msk*bhi(v.z);
                    av[6] += msk*blo(v.w); av[7] += msk*bhi(v.w);
                }
                #pragma unroll
                for (int j = 0; j < 8; ++j){
                    av[j] += __shfl_xor(av[j], 32);
                    av[j] += __shfl_xor(av[j], 16);
                }
                if (sg == 0){
                    uint4 pk;
                    pk.x = pack2bf(av[0],av[1]); pk.y = pack2bf(av[2],av[3]);
                    pk.z = pack2bf(av[4],av[5]); pk.w = pack2bf(av[6],av[7]);
                    *(uint4*)(pool + d*256 + ((c ^ (d & 15))*16)) = pk;
                }
            }
        }
        __syncthreads();

        {   // node MLP: h += ssp(agg@n_w1+b1)@n_w2+b2   (h: fp32 LDS RMW)
            floatx4 accN[2];
            #pragma unroll
            for (int ts = 0; ts < 2; ++ts){
                int task = wv + ts*8;
                int a = task & 7, dt = task >> 3;
                accN[ts] = *(const floatx4*)(bias + 256 + a*16 + quad*4);
                #pragma unroll
                for (int q = 0; q < 4; ++q){
                    short8 wf = ld_ws(ws, NW1_F + a*4 + q, lane);
                    short8 af = ld_bfrag(pool, dt, q, quad, mm);
                    accN[ts] = MFMA(wf, af, accN[ts]);
                }
            }
            __syncthreads();    // agg reads complete before T1node overwrites pool
            #pragma unroll
            for (int ts = 0; ts < 2; ++ts){
                int task = wv + ts*8;
                int a = task & 7, dt = task >> 3, d = dt*16 + mm;
                if (d < 24){
                    int cc = a*2 + (quad >> 1), off8 = (quad & 1)*8;
                    uint2 pk;
                    pk.x = pack2bf(ssp2(accN[ts][0]), ssp2(accN[ts][1]));
                    pk.y = pack2bf(ssp2(accN[ts][2]), ssp2(accN[ts][3]));
                    *(uint2*)(pool + d*256 + ((cc ^ (d & 15))*16) + off8) = pk;
                }
            }
            __syncthreads();
            #pragma unroll
            for (int ts = 0; ts < 2; ++ts){
                int task = wv + ts*8;
                int a = task & 7, dt = task >> 3;
                floatx4 acc2 = *(const floatx4*)(bias + 384 + a*16 + quad*4);
                #pragma unroll
                for (int q = 0; q < 4; ++q){
                    short8 wf = ld_ws(ws, NW2_F + a*4 + q, lane);
                    short8 tf = ld_bfrag(pool, dt, q, quad, mm);
                    acc2 = MFMA(wf, tf, acc2);
                }
                int d = dt*16 + mm;
                if (d < 24){
                    char* ha = hf + d*512 + (((a*4 + quad) ^ (d & 15))*16);
                    floatx4 hv = *(floatx4*)ha;
                    #pragma unroll
                    for (int r = 0; r < 4; ++r) hv[r] += acc2[r];
                    *(floatx4*)ha = hv;
                }
            }
        }
        __syncthreads();
    } // layers

    {   // graph head: out[mol] = sum_d (ssp(h@g_w1+b1)@g_w2 + b2); 1 task/wave
        {
            int a = wv & 3, dt = wv >> 2;
            floatx4 acc = *(const floatx4*)(g_b1 + a*16 + quad*4);
            #pragma unroll
            for (int q = 0; q < 4; ++q){
                short8 gf = ld_ws(ws, GW1_F + a*4 + q, lane);
                short8 hfr = ld_hfrag(hf, dt, q, quad, mm);
                acc = MFMA(gf, hfr, acc);
            }
            int d = dt*16 + mm;
            if (d < 24){
                uint2 pk;
                pk.x = pack2bf(ssp2(acc[0]), ssp2(acc[1]));
                pk.y = pack2bf(ssp2(acc[2]), ssp2(acc[3]));
                *(uint2*)(pool + d*128 + (a*16 + quad*4)*2) = pk;   // z[24][64] bf16
            }
        }
        __syncthreads();
        if (tid < 48){
            int dd = tid >> 1, half = tid & 1;
            float v = 0.f;
            const unsigned* zr = (const unsigned*)(pool + dd*128 + half*64);
            #pragma unroll
            for (int j = 0; j < 16; ++j){
                unsigned u = zr[j];
                v += blo(u) * g_w2[half*32 + 2*j] + bhi(u) * g_w2[half*32 + 2*j + 1];
            }
            v += __shfl_xor(v, 1);
            if (half == 0) ((float*)(pool + 4096))[dd] = v;
        }
        __syncthreads();
        if (tid == 0){
            float sum = 0.f;
            #pragma unroll
            for (int dd = 0; dd < 24; ++dd) sum += ((float*)(pool + 4096))[dd];
            out[mol] = sum + 24.0f * g_b2[0];
        }
    }
}

extern "C" void kernel_launch(void* const* d_in, const int* in_sizes, int n_in,
                              void* d_out, int out_size, void* d_ws, size_t ws_size,
                              hipStream_t stream) {
    const int*   charges = (const int*)d_in[0];
    const float* coords  = (const float*)d_in[1];
    const float* emb  = (const float*)d_in[4];
    const float* wlin = (const float*)d_in[5];
    const float* ew1  = (const float*)d_in[6];
    const float* eb1  = (const float*)d_in[7];
    const float* ew2  = (const float*)d_in[8];
    const float* eb2  = (const float*)d_in[9];
    const float* nw1  = (const float*)d_in[10];
    const float* nb1  = (const float*)d_in[11];
    const float* nw2  = (const float*)d_in[12];
    const float* nb2  = (const float*)d_in[13];
    const float* gw1  = (const float*)d_in[14];
    const float* gb1  = (const float*)d_in[15];
    const float* gw2  = (const float*)d_in[16];
    const float* gb2  = (const float*)d_in[17];
    float* out = (float*)d_out;
    char* ws = (char*)d_ws;                 // 176 KB of bf16 weight fragments

    prep_frags<<<176, 64, 0, stream>>>(wlin, ew1, ew2, nw1, nw2, gw1, ws);

    schnet_fused<<<2048, 512, 0, stream>>>(
        charges, coords, emb, ws, eb1, eb2, nb1, nb2, gb1, gw2, gb2, out);
}